// Round 12
// baseline (447.925 us; speedup 1.0000x reference)
//
#include <hip/hip_runtime.h>
#include <hip/hip_bf16.h>

#define V     49152
#define NNZ   442368
#define EPS   1e-5f
#define VOUT  12288

typedef __attribute__((ext_vector_type(8))) short bf16x8;
typedef __attribute__((ext_vector_type(4))) float f32x4;

__device__ __forceinline__ unsigned short f2b(float f) {
    __hip_bfloat16 h = __float2bfloat16(f);
    return *reinterpret_cast<unsigned short*>(&h);
}
__device__ __forceinline__ float b2f(unsigned short u) {
    return __uint_as_float((unsigned)u << 16);
}

// ---------------- row_ptr via binary search + zero partials ----------------
__global__ __launch_bounds__(256) void k_rowptr(const int* __restrict__ rows,
                                                int* __restrict__ rp,
                                                float* __restrict__ partials) {
    int id = blockIdx.x * blockDim.x + threadIdx.x;
    if (id <= V) {
        int lo = 0, hi = NNZ;
        while (lo < hi) {
            int m = (lo + hi) >> 1;
            if (rows[m] < id) lo = m + 1; else hi = m;
        }
        rp[id] = lo;
    }
    if (id < 32768) partials[id] = 0.f;
}

// ---------------- transpose x [B,V,32] f32 -> xbf [V, b*32+i] bf16 ----------------
__global__ __launch_bounds__(256) void k_xpose(const float* __restrict__ x,
                                               unsigned short* __restrict__ xbf) {
    int id = blockIdx.x * 256 + threadIdx.x;   // V*128 ids
    int i4 = id & 7;
    int b  = (id >> 3) & 15;
    int v  = id >> 7;
    float4 q = *(const float4*)&x[((size_t)b * V + v) * 32 + i4 * 4];
    ushort4 u = {f2b(q.x), f2b(q.y), f2b(q.z), f2b(q.w)};
    *(ushort4*)&xbf[(size_t)v * 512 + b * 32 + i4 * 4] = u;
}

// ---------------- W [4][32][64] f32 -> fragment-ordered bf16 Wfrag[(ks,ct,lane,j)] ----------------
__global__ __launch_bounds__(256) void k_wconv(const float* __restrict__ W,
                                               unsigned short* __restrict__ Wfrag) {
    int d = blockIdx.x * 256 + threadIdx.x;    // 8192 total
    int j = d & 7, lane = (d >> 3) & 63, ct = (d >> 9) & 3, ks = d >> 11;
    int k128 = ks * 32 + (lane >> 4) * 8 + j;
    int o = ct * 16 + (lane & 15);
    Wfrag[d] = f2b(W[k128 * 64 + o]);
}

// gather macro body: 4-deep MLP unroll
#define GATHER_LOOP(SRC)                                                        \
    float a[8] = {0.f, 0.f, 0.f, 0.f, 0.f, 0.f, 0.f, 0.f};                      \
    int n = s;                                                                  \
    for (; n + 3 < e; n += 4) {                                                 \
        int c0 = cols[n], c1 = cols[n + 1], c2 = cols[n + 2], c3 = cols[n + 3]; \
        float w0 = vals[n], w1 = vals[n + 1], w2 = vals[n + 2], w3 = vals[n + 3]; \
        union { unsigned short u[8]; uint4 q; } l0, l1, l2, l3;                 \
        l0.q = *(const uint4*)&SRC[(size_t)c0 * 512 + f0];                      \
        l1.q = *(const uint4*)&SRC[(size_t)c1 * 512 + f0];                      \
        l2.q = *(const uint4*)&SRC[(size_t)c2 * 512 + f0];                      \
        l3.q = *(const uint4*)&SRC[(size_t)c3 * 512 + f0];                      \
        _Pragma("unroll")                                                       \
        for (int j = 0; j < 8; ++j) a[j] = fmaf(w0, b2f(l0.u[j]), a[j]);        \
        _Pragma("unroll")                                                       \
        for (int j = 0; j < 8; ++j) a[j] = fmaf(w1, b2f(l1.u[j]), a[j]);        \
        _Pragma("unroll")                                                       \
        for (int j = 0; j < 8; ++j) a[j] = fmaf(w2, b2f(l2.u[j]), a[j]);        \
        _Pragma("unroll")                                                       \
        for (int j = 0; j < 8; ++j) a[j] = fmaf(w3, b2f(l3.u[j]), a[j]);        \
    }                                                                           \
    for (; n < e; ++n) {                                                        \
        int c0 = cols[n];                                                       \
        float w0 = vals[n];                                                     \
        union { unsigned short u[8]; uint4 q; } l0;                             \
        l0.q = *(const uint4*)&SRC[(size_t)c0 * 512 + f0];                      \
        _Pragma("unroll")                                                       \
        for (int j = 0; j < 8; ++j) a[j] = fmaf(w0, b2f(l0.u[j]), a[j]);        \
    }

// ---------------- X1 = L @ X0 ----------------
__global__ __launch_bounds__(256) void k_spmm1(const unsigned short* __restrict__ xbf,
                                               const int* __restrict__ cols,
                                               const float* __restrict__ vals,
                                               const int* __restrict__ rp,
                                               unsigned short* __restrict__ X1) {
    int t = threadIdx.x;
    int wave = t >> 6, lane = t & 63;
    int v = blockIdx.x * 4 + wave;
    int f0 = lane * 8;
    int s = rp[v], e = rp[v + 1];
    GATHER_LOOP(xbf)
    union { unsigned short u[8]; uint4 q; } st;
#pragma unroll
    for (int j = 0; j < 8; ++j) st.u[j] = f2b(a[j]);
    *(uint4*)&X1[(size_t)v * 512 + f0] = st.q;
}

// ---------------- X2 = 2 L @ X1 - X0 ----------------
__global__ __launch_bounds__(256) void k_spmm2(const unsigned short* __restrict__ xbf,
                                               const int* __restrict__ cols,
                                               const float* __restrict__ vals,
                                               const int* __restrict__ rp,
                                               const unsigned short* __restrict__ X1,
                                               unsigned short* __restrict__ X2) {
    int t = threadIdx.x;
    int wave = t >> 6, lane = t & 63;
    int v = blockIdx.x * 4 + wave;
    int f0 = lane * 8;
    int s = rp[v], e = rp[v + 1];
    GATHER_LOOP(X1)
    union { unsigned short u[8]; uint4 q; } x0;
    x0.q = *(const uint4*)&xbf[(size_t)v * 512 + f0];
    union { unsigned short u[8]; uint4 q; } st;
#pragma unroll
    for (int j = 0; j < 8; ++j) st.u[j] = f2b(2.f * a[j] - b2f(x0.u[j]));
    *(uint4*)&X2[(size_t)v * 512 + f0] = st.q;
}

// ---------------- X3 = 2 L @ X2 - X1 ----------------
__global__ __launch_bounds__(256) void k_spmm3(const unsigned short* __restrict__ X1,
                                               const int* __restrict__ cols,
                                               const float* __restrict__ vals,
                                               const int* __restrict__ rp,
                                               const unsigned short* __restrict__ X2,
                                               unsigned short* __restrict__ X3) {
    int t = threadIdx.x;
    int wave = t >> 6, lane = t & 63;
    int v = blockIdx.x * 4 + wave;
    int f0 = lane * 8;
    int s = rp[v], e = rp[v + 1];
    GATHER_LOOP(X2)
    union { unsigned short u[8]; uint4 q; } p1;
    p1.q = *(const uint4*)&X1[(size_t)v * 512 + f0];
    union { unsigned short u[8]; uint4 q; } st;
#pragma unroll
    for (int j = 0; j < 8; ++j) st.u[j] = f2b(2.f * a[j] - b2f(p1.u[j]));
    *(uint4*)&X3[(size_t)v * 512 + f0] = st.q;
}

// ---------------- MFMA einsum + BN bucket-partials ----------------
// One wave per vertex (16 rows), 4 col-tiles of 16; K = 4 steps of 32.
__global__ __launch_bounds__(256) void k_einsum(const unsigned short* __restrict__ xbf,
                                                const unsigned short* __restrict__ X1,
                                                const unsigned short* __restrict__ X2,
                                                const unsigned short* __restrict__ X3,
                                                const unsigned short* __restrict__ Wfrag,
                                                unsigned short* __restrict__ Y,
                                                float* __restrict__ partials) {
    __shared__ unsigned short sB[8192];   // 16 KB, fragment-ordered W
    __shared__ unsigned short sY[4096];   // 8 KB bounce for coalesced Y write
    __shared__ float lsum[64], lsq[64];

    int t = threadIdx.x;
    int wave = t >> 6, lane = t & 63;
    int v = blockIdx.x * 4 + wave;

    // stage Wfrag -> LDS (4 x uint4 per thread, coalesced)
#pragma unroll
    for (int m = 0; m < 4; ++m) {
        int d = t + m * 256;
        *(uint4*)&sB[d * 8] = *(const uint4*)&Wfrag[d * 8];
    }
    if (t < 64) { lsum[t] = 0.f; lsq[t] = 0.f; }
    __syncthreads();

    f32x4 acc[4];
#pragma unroll
    for (int ct = 0; ct < 4; ++ct) acc[ct] = (f32x4){0.f, 0.f, 0.f, 0.f};

    const unsigned short* srcs[4] = {xbf, X1, X2, X3};
    size_t abase = (size_t)v * 512 + (lane & 15) * 32 + (lane >> 4) * 8;
#pragma unroll
    for (int ks = 0; ks < 4; ++ks) {
        bf16x8 a = *(const bf16x8*)&srcs[ks][abase];
#pragma unroll
        for (int ct = 0; ct < 4; ++ct) {
            bf16x8 b = *(const bf16x8*)&sB[((ks * 4 + ct) * 64 + lane) * 8];
            acc[ct] = __builtin_amdgcn_mfma_f32_16x16x32_bf16(a, b, acc[ct], 0, 0, 0);
        }
    }

    // BN partial sums from exact accumulators (LDS reduce)
#pragma unroll
    for (int ct = 0; ct < 4; ++ct) {
        float ss = acc[ct].x + acc[ct].y + acc[ct].z + acc[ct].w;
        float qq = acc[ct].x * acc[ct].x + acc[ct].y * acc[ct].y
                 + acc[ct].z * acc[ct].z + acc[ct].w * acc[ct].w;
        atomicAdd(&lsum[ct * 16 + (lane & 15)], ss);
        atomicAdd(&lsq[ct * 16 + (lane & 15)], qq);
    }

    // bounce C into LDS: sY[wave][b][o], b = (lane>>4)*4+g, o = ct*16+(lane&15)
#pragma unroll
    for (int ct = 0; ct < 4; ++ct) {
        int o = ct * 16 + (lane & 15);
        int bb = (lane >> 4) * 4;
        sY[wave * 1024 + (bb + 0) * 64 + o] = f2b(acc[ct].x);
        sY[wave * 1024 + (bb + 1) * 64 + o] = f2b(acc[ct].y);
        sY[wave * 1024 + (bb + 2) * 64 + o] = f2b(acc[ct].z);
        sY[wave * 1024 + (bb + 3) * 64 + o] = f2b(acc[ct].w);
    }
    __syncthreads();

    // coalesced Y write: block covers 4 vertex-rows x 1024 bf16 = 8 KB
    size_t ybase = (size_t)blockIdx.x * 4096 + t * 16;
    *(uint4*)&Y[ybase]     = *(const uint4*)&sY[t * 16];
    *(uint4*)&Y[ybase + 8] = *(const uint4*)&sY[t * 16 + 8];

    // bucketized global partials: 256 buckets -> ~48 adds/address over kernel lifetime
    if (t < 128) {
        float val = (t < 64) ? lsum[t] : lsq[t - 64];
        atomicAdd(&partials[(blockIdx.x & 255) * 128 + t], val);
    }
}

// ---------------- finalize BN scale/shift from 256 bucket rows ----------------
__global__ void k_bnfin(const float* __restrict__ partials,
                        const float* __restrict__ gamma, const float* __restrict__ beta,
                        float* __restrict__ stats) {
    __shared__ float tot[128];
    int t = threadIdx.x;   // 128 threads
    float s = 0.f;
    for (int i = 0; i < 256; ++i) s += partials[i * 128 + t];
    tot[t] = s;
    __syncthreads();
    if (t < 64) {
        float n = (float)(16 * V);
        float mean = tot[t] / n;
        float var = tot[64 + t] / n - mean * mean;
        float sc = gamma[t] * rsqrtf(var + EPS);
        stats[128 + t] = sc;
        stats[192 + t] = beta[t] - mean * sc;
    }
}

// ---------------- BN apply + ReLU + pool(4), bf16 y in ----------------
__global__ __launch_bounds__(256) void k_pool(const unsigned short* __restrict__ Y,
                                              const float* __restrict__ stats,
                                              float* __restrict__ out) {
    int id = blockIdx.x * blockDim.x + threadIdx.x;
    int o4 = id & 15;
    int b  = (id >> 4) & 15;
    int vp = id >> 8;
    float4 sc = *(const float4*)&stats[128 + o4 * 4];
    float4 sh = *(const float4*)&stats[192 + o4 * 4];
    float ax = 0.f, ay = 0.f, az = 0.f, aw = 0.f;
#pragma unroll
    for (int j = 0; j < 4; ++j) {
        ushort4 u = *(const ushort4*)&Y[(size_t)((vp * 4 + j) * 16 + b) * 64 + o4 * 4];
        float tx = b2f(u.x), ty = b2f(u.y), tz = b2f(u.z), tw = b2f(u.w);
        ax += fmaxf(fmaf(tx, sc.x, sh.x), 0.f);
        ay += fmaxf(fmaf(ty, sc.y, sh.y), 0.f);
        az += fmaxf(fmaf(tz, sc.z, sh.z), 0.f);
        aw += fmaxf(fmaf(tw, sc.w, sh.w), 0.f);
    }
    float4 res = {ax * 0.25f, ay * 0.25f, az * 0.25f, aw * 0.25f};
    *(float4*)&out[(size_t)((b * VOUT + vp) * 16 + o4) * 4] = res;
}

extern "C" void kernel_launch(void* const* d_in, const int* in_sizes, int n_in,
                              void* d_out, int out_size, void* d_ws, size_t ws_size,
                              hipStream_t stream) {
    const float* x     = (const float*)d_in[0];
    const float* vals  = (const float*)d_in[1];
    const float* W     = (const float*)d_in[2];
    const float* gamma = (const float*)d_in[3];
    const float* beta  = (const float*)d_in[4];
    const int*   rows  = (const int*)d_in[5];
    const int*   cols  = (const int*)d_in[6];
    float* out = (float*)d_out;

    char* ws = (char*)d_ws;
    unsigned short* xbf = (unsigned short*)ws;                    //  50,331,648 B
    unsigned short* X1  = (unsigned short*)(ws + 50331648UL);     //  50,331,648 B
    unsigned short* X2  = (unsigned short*)(ws + 100663296UL);    //  50,331,648 B
    unsigned short* X3  = (unsigned short*)(ws + 150994944UL);    //  50,331,648 B
    unsigned short* Y   = (unsigned short*)(ws + 201326592UL);    // 100,663,296 B (ends 301,989,888)
    int*   rp    = (int*)(ws + 301989888UL);                      // 196,612 B (ends 302,186,500)
    float* stats = (float*)(ws + 302186560UL);                    // 1 KB
    unsigned short* Wfrag = (unsigned short*)(ws + 302187584UL);  // 16 KB (ends 302,203,968)
    float* partials = (float*)(ws + 302203968UL);                 // 131,072 B (ends 302,335,040)

    k_rowptr<<<193, 256, 0, stream>>>(rows, rp, partials);
    k_xpose<<<V * 128 / 256, 256, 0, stream>>>(x, xbf);
    k_wconv<<<32, 256, 0, stream>>>(W, Wfrag);
    k_spmm1<<<V / 4, 256, 0, stream>>>(xbf, cols, vals, rp, X1);
    k_spmm2<<<V / 4, 256, 0, stream>>>(xbf, cols, vals, rp, X1, X2);
    k_spmm3<<<V / 4, 256, 0, stream>>>(X1, cols, vals, rp, X2, X3);
    k_einsum<<<V / 4, 256, 0, stream>>>(xbf, X1, X2, X3, Wfrag, Y, partials);
    k_bnfin<<<1, 128, 0, stream>>>(partials, gamma, beta, stats);
    k_pool<<<12288, 256, 0, stream>>>(Y, stats, out);
}

// Round 13
// 353.938 us; speedup vs baseline: 1.2655x; 1.2655x over previous
//
#include <hip/hip_runtime.h>
#include <hip/hip_bf16.h>

#define V     49152
#define NNZ   442368
#define EPS   1e-5f
#define VOUT  12288

typedef __attribute__((ext_vector_type(8))) short bf16x8;
typedef __attribute__((ext_vector_type(4))) float f32x4;

__device__ __forceinline__ unsigned short f2b(float f) {
    __hip_bfloat16 h = __float2bfloat16(f);
    return *reinterpret_cast<unsigned short*>(&h);
}
__device__ __forceinline__ float b2f(unsigned short u) {
    return __uint_as_float((unsigned)u << 16);
}

// ---------------- row_ptr via binary search ----------------
__global__ __launch_bounds__(256) void k_rowptr(const int* __restrict__ rows,
                                                int* __restrict__ rp) {
    int id = blockIdx.x * blockDim.x + threadIdx.x;
    if (id <= V) {
        int lo = 0, hi = NNZ;
        while (lo < hi) {
            int m = (lo + hi) >> 1;
            if (rows[m] < id) lo = m + 1; else hi = m;
        }
        rp[id] = lo;
    }
}

// ---------------- transpose x [B,V,32] f32 -> xbf [V, b*32+i] bf16 ----------------
__global__ __launch_bounds__(256) void k_xpose(const float* __restrict__ x,
                                               unsigned short* __restrict__ xbf) {
    int id = blockIdx.x * 256 + threadIdx.x;   // V*128 ids
    int i4 = id & 7;
    int b  = (id >> 3) & 15;
    int v  = id >> 7;
    float4 q = *(const float4*)&x[((size_t)b * V + v) * 32 + i4 * 4];
    ushort4 u = {f2b(q.x), f2b(q.y), f2b(q.z), f2b(q.w)};
    *(ushort4*)&xbf[(size_t)v * 512 + b * 32 + i4 * 4] = u;
}

// ---------------- W [4][32][64] f32 -> fragment-ordered bf16 Wfrag[(ks,ct,lane,j)] ----------------
__global__ __launch_bounds__(256) void k_wconv(const float* __restrict__ W,
                                               unsigned short* __restrict__ Wfrag) {
    int d = blockIdx.x * 256 + threadIdx.x;    // 8192 total
    int j = d & 7, lane = (d >> 3) & 63, ct = (d >> 9) & 3, ks = d >> 11;
    int k128 = ks * 32 + (lane >> 4) * 8 + j;
    int o = ct * 16 + (lane & 15);
    Wfrag[d] = f2b(W[k128 * 64 + o]);
}

// gather macro body: 4-deep MLP unroll
#define GATHER_LOOP(SRC)                                                        \
    float a[8] = {0.f, 0.f, 0.f, 0.f, 0.f, 0.f, 0.f, 0.f};                      \
    int n = s;                                                                  \
    for (; n + 3 < e; n += 4) {                                                 \
        int c0 = cols[n], c1 = cols[n + 1], c2 = cols[n + 2], c3 = cols[n + 3]; \
        float w0 = vals[n], w1 = vals[n + 1], w2 = vals[n + 2], w3 = vals[n + 3]; \
        union { unsigned short u[8]; uint4 q; } l0, l1, l2, l3;                 \
        l0.q = *(const uint4*)&SRC[(size_t)c0 * 512 + f0];                      \
        l1.q = *(const uint4*)&SRC[(size_t)c1 * 512 + f0];                      \
        l2.q = *(const uint4*)&SRC[(size_t)c2 * 512 + f0];                      \
        l3.q = *(const uint4*)&SRC[(size_t)c3 * 512 + f0];                      \
        _Pragma("unroll")                                                       \
        for (int j = 0; j < 8; ++j) a[j] = fmaf(w0, b2f(l0.u[j]), a[j]);        \
        _Pragma("unroll")                                                       \
        for (int j = 0; j < 8; ++j) a[j] = fmaf(w1, b2f(l1.u[j]), a[j]);        \
        _Pragma("unroll")                                                       \
        for (int j = 0; j < 8; ++j) a[j] = fmaf(w2, b2f(l2.u[j]), a[j]);        \
        _Pragma("unroll")                                                       \
        for (int j = 0; j < 8; ++j) a[j] = fmaf(w3, b2f(l3.u[j]), a[j]);        \
    }                                                                           \
    for (; n < e; ++n) {                                                        \
        int c0 = cols[n];                                                       \
        float w0 = vals[n];                                                     \
        union { unsigned short u[8]; uint4 q; } l0;                             \
        l0.q = *(const uint4*)&SRC[(size_t)c0 * 512 + f0];                      \
        _Pragma("unroll")                                                       \
        for (int j = 0; j < 8; ++j) a[j] = fmaf(w0, b2f(l0.u[j]), a[j]);        \
    }

// ---------------- X1 = L @ X0 ----------------
__global__ __launch_bounds__(256) void k_spmm1(const unsigned short* __restrict__ xbf,
                                               const int* __restrict__ cols,
                                               const float* __restrict__ vals,
                                               const int* __restrict__ rp,
                                               unsigned short* __restrict__ X1) {
    int t = threadIdx.x;
    int wave = t >> 6, lane = t & 63;
    int v = blockIdx.x * 4 + wave;
    int f0 = lane * 8;
    int s = rp[v], e = rp[v + 1];
    GATHER_LOOP(xbf)
    union { unsigned short u[8]; uint4 q; } st;
#pragma unroll
    for (int j = 0; j < 8; ++j) st.u[j] = f2b(a[j]);
    *(uint4*)&X1[(size_t)v * 512 + f0] = st.q;
}

// ---------------- X2 = 2 L @ X1 - X0 ----------------
__global__ __launch_bounds__(256) void k_spmm2(const unsigned short* __restrict__ xbf,
                                               const int* __restrict__ cols,
                                               const float* __restrict__ vals,
                                               const int* __restrict__ rp,
                                               const unsigned short* __restrict__ X1,
                                               unsigned short* __restrict__ X2) {
    int t = threadIdx.x;
    int wave = t >> 6, lane = t & 63;
    int v = blockIdx.x * 4 + wave;
    int f0 = lane * 8;
    int s = rp[v], e = rp[v + 1];
    GATHER_LOOP(X1)
    union { unsigned short u[8]; uint4 q; } x0;
    x0.q = *(const uint4*)&xbf[(size_t)v * 512 + f0];
    union { unsigned short u[8]; uint4 q; } st;
#pragma unroll
    for (int j = 0; j < 8; ++j) st.u[j] = f2b(2.f * a[j] - b2f(x0.u[j]));
    *(uint4*)&X2[(size_t)v * 512 + f0] = st.q;
}

// ---------------- X3 = 2 L @ X2 - X1 ----------------
__global__ __launch_bounds__(256) void k_spmm3(const unsigned short* __restrict__ X1,
                                               const int* __restrict__ cols,
                                               const float* __restrict__ vals,
                                               const int* __restrict__ rp,
                                               const unsigned short* __restrict__ X2,
                                               unsigned short* __restrict__ X3) {
    int t = threadIdx.x;
    int wave = t >> 6, lane = t & 63;
    int v = blockIdx.x * 4 + wave;
    int f0 = lane * 8;
    int s = rp[v], e = rp[v + 1];
    GATHER_LOOP(X2)
    union { unsigned short u[8]; uint4 q; } p1;
    p1.q = *(const uint4*)&X1[(size_t)v * 512 + f0];
    union { unsigned short u[8]; uint4 q; } st;
#pragma unroll
    for (int j = 0; j < 8; ++j) st.u[j] = f2b(2.f * a[j] - b2f(p1.u[j]));
    *(uint4*)&X3[(size_t)v * 512 + f0] = st.q;
}

// ---------------- MFMA einsum + non-atomic BN partials ----------------
// One wave per vertex (16 rows), 4 col-tiles of 16; K = 4 steps of 32.
// Block's 128-float BN partial is written into the block's OWN (fully consumed)
// X3 slice: pout + bid*1024 floats. No atomics anywhere.
__global__ __launch_bounds__(256) void k_einsum(const unsigned short* __restrict__ xbf,
                                                const unsigned short* __restrict__ X1,
                                                const unsigned short* __restrict__ X2,
                                                const unsigned short* __restrict__ X3,
                                                const unsigned short* __restrict__ Wfrag,
                                                unsigned short* __restrict__ Y,
                                                float* __restrict__ pout) {
    __shared__ unsigned short sB[8192];   // 16 KB, fragment-ordered W
    __shared__ unsigned short sY[4096];   // 8 KB bounce for coalesced Y write
    __shared__ float sP[512];             // 2 KB: per-wave channel partials [wave][128]

    int t = threadIdx.x;
    int wave = t >> 6, lane = t & 63;
    int v = blockIdx.x * 4 + wave;

    // stage Wfrag -> LDS (4 x uint4 per thread, coalesced)
#pragma unroll
    for (int m = 0; m < 4; ++m) {
        int d = t + m * 256;
        *(uint4*)&sB[d * 8] = *(const uint4*)&Wfrag[d * 8];
    }
    __syncthreads();

    f32x4 acc[4];
#pragma unroll
    for (int ct = 0; ct < 4; ++ct) acc[ct] = (f32x4){0.f, 0.f, 0.f, 0.f};

    const unsigned short* srcs[4] = {xbf, X1, X2, X3};
    size_t abase = (size_t)v * 512 + (lane & 15) * 32 + (lane >> 4) * 8;
#pragma unroll
    for (int ks = 0; ks < 4; ++ks) {
        bf16x8 a = *(const bf16x8*)&srcs[ks][abase];
#pragma unroll
        for (int ct = 0; ct < 4; ++ct) {
            bf16x8 b = *(const bf16x8*)&sB[((ks * 4 + ct) * 64 + lane) * 8];
            acc[ct] = __builtin_amdgcn_mfma_f32_16x16x32_bf16(a, b, acc[ct], 0, 0, 0);
        }
    }

    // BN partials: shfl-reduce across the 4 lanes sharing (lane&15); no atomics
#pragma unroll
    for (int ct = 0; ct < 4; ++ct) {
        float ss = acc[ct].x + acc[ct].y + acc[ct].z + acc[ct].w;
        float qq = acc[ct].x * acc[ct].x + acc[ct].y * acc[ct].y
                 + acc[ct].z * acc[ct].z + acc[ct].w * acc[ct].w;
        ss += __shfl_xor(ss, 16); ss += __shfl_xor(ss, 32);
        qq += __shfl_xor(qq, 16); qq += __shfl_xor(qq, 32);
        if (lane < 16) {
            sP[wave * 128 + ct * 16 + lane]      = ss;
            sP[wave * 128 + 64 + ct * 16 + lane] = qq;
        }
    }

    // bounce C into LDS: sY[wave][b][o], b = (lane>>4)*4+g, o = ct*16+(lane&15)
#pragma unroll
    for (int ct = 0; ct < 4; ++ct) {
        int o = ct * 16 + (lane & 15);
        int bb = (lane >> 4) * 4;
        sY[wave * 1024 + (bb + 0) * 64 + o] = f2b(acc[ct].x);
        sY[wave * 1024 + (bb + 1) * 64 + o] = f2b(acc[ct].y);
        sY[wave * 1024 + (bb + 2) * 64 + o] = f2b(acc[ct].z);
        sY[wave * 1024 + (bb + 3) * 64 + o] = f2b(acc[ct].w);
    }
    __syncthreads();   // also guarantees all waves finished their X3 A-reads

    // coalesced Y write: block covers 4 vertex-rows x 1024 bf16 = 8 KB
    size_t ybase = (size_t)blockIdx.x * 4096 + t * 16;
    *(uint4*)&Y[ybase]     = *(const uint4*)&sY[t * 16];
    *(uint4*)&Y[ybase + 8] = *(const uint4*)&sY[t * 16 + 8];

    // non-atomic partial write into this block's consumed X3 slice (1024-float stride)
    if (t < 128)
        pout[(size_t)blockIdx.x * 1024 + t] =
            sP[t] + sP[128 + t] + sP[256 + t] + sP[384 + t];
}

// ---------------- reduce strided partials [12288 rows x 1024-stride] -> partials2[48][128] ----------------
__global__ __launch_bounds__(128) void k_bnred2(const float* __restrict__ P,
                                                float* __restrict__ partials2) {
    int t = threadIdx.x;   // 128
    size_t base = (size_t)blockIdx.x * 256;
    float s = 0.f;
    for (int r = 0; r < 256; ++r)
        s += P[(base + r) * 1024 + t];
    partials2[blockIdx.x * 128 + t] = s;
}

// ---------------- finalize BN scale/shift from 48 partial rows ----------------
__global__ void k_bnfin(const float* __restrict__ partials2,
                        const float* __restrict__ gamma, const float* __restrict__ beta,
                        float* __restrict__ stats) {
    __shared__ float tot[128];
    int t = threadIdx.x;   // 128 threads
    float s = 0.f;
    for (int i = 0; i < 48; ++i) s += partials2[i * 128 + t];
    tot[t] = s;
    __syncthreads();
    if (t < 64) {
        float n = (float)(16 * V);
        float mean = tot[t] / n;
        float var = tot[64 + t] / n - mean * mean;
        float sc = gamma[t] * rsqrtf(var + EPS);
        stats[128 + t] = sc;
        stats[192 + t] = beta[t] - mean * sc;
    }
}

// ---------------- BN apply + ReLU + pool(4), bf16 y in ----------------
__global__ __launch_bounds__(256) void k_pool(const unsigned short* __restrict__ Y,
                                              const float* __restrict__ stats,
                                              float* __restrict__ out) {
    int id = blockIdx.x * blockDim.x + threadIdx.x;
    int o4 = id & 15;
    int b  = (id >> 4) & 15;
    int vp = id >> 8;
    float4 sc = *(const float4*)&stats[128 + o4 * 4];
    float4 sh = *(const float4*)&stats[192 + o4 * 4];
    float ax = 0.f, ay = 0.f, az = 0.f, aw = 0.f;
#pragma unroll
    for (int j = 0; j < 4; ++j) {
        ushort4 u = *(const ushort4*)&Y[(size_t)((vp * 4 + j) * 16 + b) * 64 + o4 * 4];
        float tx = b2f(u.x), ty = b2f(u.y), tz = b2f(u.z), tw = b2f(u.w);
        ax += fmaxf(fmaf(tx, sc.x, sh.x), 0.f);
        ay += fmaxf(fmaf(ty, sc.y, sh.y), 0.f);
        az += fmaxf(fmaf(tz, sc.z, sh.z), 0.f);
        aw += fmaxf(fmaf(tw, sc.w, sh.w), 0.f);
    }
    float4 res = {ax * 0.25f, ay * 0.25f, az * 0.25f, aw * 0.25f};
    *(float4*)&out[(size_t)((b * VOUT + vp) * 16 + o4) * 4] = res;
}

extern "C" void kernel_launch(void* const* d_in, const int* in_sizes, int n_in,
                              void* d_out, int out_size, void* d_ws, size_t ws_size,
                              hipStream_t stream) {
    const float* x     = (const float*)d_in[0];
    const float* vals  = (const float*)d_in[1];
    const float* W     = (const float*)d_in[2];
    const float* gamma = (const float*)d_in[3];
    const float* beta  = (const float*)d_in[4];
    const int*   rows  = (const int*)d_in[5];
    const int*   cols  = (const int*)d_in[6];
    float* out = (float*)d_out;

    char* ws = (char*)d_ws;
    unsigned short* xbf = (unsigned short*)ws;                    //  50,331,648 B
    unsigned short* X1  = (unsigned short*)(ws + 50331648UL);     //  50,331,648 B
    unsigned short* X2  = (unsigned short*)(ws + 100663296UL);    //  50,331,648 B
    unsigned short* X3  = (unsigned short*)(ws + 150994944UL);    //  50,331,648 B
    unsigned short* Y   = (unsigned short*)(ws + 201326592UL);    // 100,663,296 B (ends 301,989,888)
    int*   rp    = (int*)(ws + 301989888UL);                      // 196,612 B (ends 302,186,500)
    float* stats = (float*)(ws + 302186560UL);                    // 1 KB
    unsigned short* Wfrag = (unsigned short*)(ws + 302187584UL);  // 16 KB (ends 302,203,968)
    float* partials2 = (float*)(ws + 302204032UL);                // 24,576 B (ends 302,228,608)

    k_rowptr<<<193, 256, 0, stream>>>(rows, rp);
    k_xpose<<<V * 128 / 256, 256, 0, stream>>>(x, xbf);
    k_wconv<<<32, 256, 0, stream>>>(W, Wfrag);
    k_spmm1<<<V / 4, 256, 0, stream>>>(xbf, cols, vals, rp, X1);
    k_spmm2<<<V / 4, 256, 0, stream>>>(xbf, cols, vals, rp, X1, X2);
    k_spmm3<<<V / 4, 256, 0, stream>>>(X1, cols, vals, rp, X2, X3);
    k_einsum<<<V / 4, 256, 0, stream>>>(xbf, X1, X2, X3, Wfrag, Y, (float*)X3);
    k_bnred2<<<48, 128, 0, stream>>>((const float*)X3, partials2);
    k_bnfin<<<1, 128, 0, stream>>>(partials2, gamma, beta, stats);
    k_pool<<<12288, 256, 0, stream>>>(Y, stats, out);
}

// Round 14
// 350.998 us; speedup vs baseline: 1.2761x; 1.0084x over previous
//
#include <hip/hip_runtime.h>
#include <hip/hip_bf16.h>

#define V     49152
#define NNZ   442368
#define EPS   1e-5f
#define VOUT  12288

typedef __attribute__((ext_vector_type(8))) short bf16x8;
typedef __attribute__((ext_vector_type(4))) float f32x4;

__device__ __forceinline__ unsigned short f2b(float f) {
    __hip_bfloat16 h = __float2bfloat16(f);
    return *reinterpret_cast<unsigned short*>(&h);
}
__device__ __forceinline__ float b2f(unsigned short u) {
    return __uint_as_float((unsigned)u << 16);
}

// ---------------- row_ptr via binary search ----------------
__global__ __launch_bounds__(256) void k_rowptr(const int* __restrict__ rows,
                                                int* __restrict__ rp) {
    int id = blockIdx.x * blockDim.x + threadIdx.x;
    if (id <= V) {
        int lo = 0, hi = NNZ;
        while (lo < hi) {
            int m = (lo + hi) >> 1;
            if (rows[m] < id) lo = m + 1; else hi = m;
        }
        rp[id] = lo;
    }
}

// ---------------- transpose x [B,V,32] f32 -> xbf [V, b*32+i] bf16 ----------------
__global__ __launch_bounds__(256) void k_xpose(const float* __restrict__ x,
                                               unsigned short* __restrict__ xbf) {
    int id = blockIdx.x * 256 + threadIdx.x;   // V*128 ids
    int i4 = id & 7;
    int b  = (id >> 3) & 15;
    int v  = id >> 7;
    float4 q = *(const float4*)&x[((size_t)b * V + v) * 32 + i4 * 4];
    ushort4 u = {f2b(q.x), f2b(q.y), f2b(q.z), f2b(q.w)};
    *(ushort4*)&xbf[(size_t)v * 512 + b * 32 + i4 * 4] = u;
}

// ---------------- W [4][32][64] f32 -> fragment-ordered bf16 Wfrag[(ks,ct,lane,j)] ----------------
__global__ __launch_bounds__(256) void k_wconv(const float* __restrict__ W,
                                               unsigned short* __restrict__ Wfrag) {
    int d = blockIdx.x * 256 + threadIdx.x;    // 8192 total
    int j = d & 7, lane = (d >> 3) & 63, ct = (d >> 9) & 3, ks = d >> 11;
    int k128 = ks * 32 + (lane >> 4) * 8 + j;
    int o = ct * 16 + (lane & 15);
    Wfrag[d] = f2b(W[k128 * 64 + o]);
}

// gather macro body: 4-deep MLP unroll
#define GATHER_LOOP(SRC)                                                        \
    float a[8] = {0.f, 0.f, 0.f, 0.f, 0.f, 0.f, 0.f, 0.f};                      \
    int n = s;                                                                  \
    for (; n + 3 < e; n += 4) {                                                 \
        int c0 = cols[n], c1 = cols[n + 1], c2 = cols[n + 2], c3 = cols[n + 3]; \
        float w0 = vals[n], w1 = vals[n + 1], w2 = vals[n + 2], w3 = vals[n + 3]; \
        union { unsigned short u[8]; uint4 q; } l0, l1, l2, l3;                 \
        l0.q = *(const uint4*)&SRC[(size_t)c0 * 512 + f0];                      \
        l1.q = *(const uint4*)&SRC[(size_t)c1 * 512 + f0];                      \
        l2.q = *(const uint4*)&SRC[(size_t)c2 * 512 + f0];                      \
        l3.q = *(const uint4*)&SRC[(size_t)c3 * 512 + f0];                      \
        _Pragma("unroll")                                                       \
        for (int j = 0; j < 8; ++j) a[j] = fmaf(w0, b2f(l0.u[j]), a[j]);        \
        _Pragma("unroll")                                                       \
        for (int j = 0; j < 8; ++j) a[j] = fmaf(w1, b2f(l1.u[j]), a[j]);        \
        _Pragma("unroll")                                                       \
        for (int j = 0; j < 8; ++j) a[j] = fmaf(w2, b2f(l2.u[j]), a[j]);        \
        _Pragma("unroll")                                                       \
        for (int j = 0; j < 8; ++j) a[j] = fmaf(w3, b2f(l3.u[j]), a[j]);        \
    }                                                                           \
    for (; n < e; ++n) {                                                        \
        int c0 = cols[n];                                                       \
        float w0 = vals[n];                                                     \
        union { unsigned short u[8]; uint4 q; } l0;                             \
        l0.q = *(const uint4*)&SRC[(size_t)c0 * 512 + f0];                      \
        _Pragma("unroll")                                                       \
        for (int j = 0; j < 8; ++j) a[j] = fmaf(w0, b2f(l0.u[j]), a[j]);        \
    }

// ---------------- X1 = L @ X0 ----------------
__global__ __launch_bounds__(256) void k_spmm1(const unsigned short* __restrict__ xbf,
                                               const int* __restrict__ cols,
                                               const float* __restrict__ vals,
                                               const int* __restrict__ rp,
                                               unsigned short* __restrict__ X1) {
    int t = threadIdx.x;
    int wave = t >> 6, lane = t & 63;
    int v = blockIdx.x * 4 + wave;
    int f0 = lane * 8;
    int s = rp[v], e = rp[v + 1];
    GATHER_LOOP(xbf)
    union { unsigned short u[8]; uint4 q; } st;
#pragma unroll
    for (int j = 0; j < 8; ++j) st.u[j] = f2b(a[j]);
    *(uint4*)&X1[(size_t)v * 512 + f0] = st.q;
}

// ---------------- X2 = 2 L @ X1 - X0 ----------------
__global__ __launch_bounds__(256) void k_spmm2(const unsigned short* __restrict__ xbf,
                                               const int* __restrict__ cols,
                                               const float* __restrict__ vals,
                                               const int* __restrict__ rp,
                                               const unsigned short* __restrict__ X1,
                                               unsigned short* __restrict__ X2) {
    int t = threadIdx.x;
    int wave = t >> 6, lane = t & 63;
    int v = blockIdx.x * 4 + wave;
    int f0 = lane * 8;
    int s = rp[v], e = rp[v + 1];
    GATHER_LOOP(X1)
    union { unsigned short u[8]; uint4 q; } x0;
    x0.q = *(const uint4*)&xbf[(size_t)v * 512 + f0];
    union { unsigned short u[8]; uint4 q; } st;
#pragma unroll
    for (int j = 0; j < 8; ++j) st.u[j] = f2b(2.f * a[j] - b2f(x0.u[j]));
    *(uint4*)&X2[(size_t)v * 512 + f0] = st.q;
}

// ---- fused: X3 gather (regs, shfl to A-frag) + MFMA einsum + BN per-wave partials + Y ----
// One wave per vertex. X3 never touches HBM. Only barriers: after W-stage, before sY write-out.
__global__ __launch_bounds__(256) void k_cheb(const unsigned short* __restrict__ xbf,
                                              const unsigned short* __restrict__ X1,
                                              const unsigned short* __restrict__ X2,
                                              const unsigned short* __restrict__ Wfrag,
                                              const int* __restrict__ cols,
                                              const float* __restrict__ vals,
                                              const int* __restrict__ rp,
                                              unsigned short* __restrict__ Y,
                                              float* __restrict__ pout) {
    __shared__ unsigned short sB[8192];   // 16 KB, fragment-ordered W
    __shared__ unsigned short sY[4096];   // 8 KB bounce for coalesced Y write

    int t = threadIdx.x;
    int wave = t >> 6, lane = t & 63;
    int v = blockIdx.x * 4 + wave;

    // stage Wfrag -> LDS (completes under the gather; barrier comes after gather)
#pragma unroll
    for (int m = 0; m < 4; ++m) {
        int d = t + m * 256;
        *(uint4*)&sB[d * 8] = *(const uint4*)&Wfrag[d * 8];
    }

    // ---- gather X3 row of v into registers (lane holds features [8*lane, 8*lane+8)) ----
    int f0 = lane * 8;
    int s = rp[v], e = rp[v + 1];
    GATHER_LOOP(X2)
    union { unsigned short u[8]; uint4 q; } p1;
    p1.q = *(const uint4*)&X1[(size_t)v * 512 + f0];
    // X3 = 2a - X1, packed to bf16 pairs for shfl
    uint4 packed;
    packed.x = (unsigned)f2b(2.f * a[0] - b2f(p1.u[0])) | ((unsigned)f2b(2.f * a[1] - b2f(p1.u[1])) << 16);
    packed.y = (unsigned)f2b(2.f * a[2] - b2f(p1.u[2])) | ((unsigned)f2b(2.f * a[3] - b2f(p1.u[3])) << 16);
    packed.z = (unsigned)f2b(2.f * a[4] - b2f(p1.u[4])) | ((unsigned)f2b(2.f * a[5] - b2f(p1.u[5])) << 16);
    packed.w = (unsigned)f2b(2.f * a[6] - b2f(p1.u[6])) | ((unsigned)f2b(2.f * a[7] - b2f(p1.u[7])) << 16);
    // A-frag lane m needs lane s(m) = (m&15)*4 + (m>>4)'s 8 features
    int src = (lane & 15) * 4 + (lane >> 4);
    union { uint4 q; bf16x8 h; } a3;
    a3.q.x = __shfl(packed.x, src);
    a3.q.y = __shfl(packed.y, src);
    a3.q.z = __shfl(packed.z, src);
    a3.q.w = __shfl(packed.w, src);

    __syncthreads();   // sB ready (staged long ago)

    // ---- MFMA: ks = 0,1,2 from global, ks = 3 from registers ----
    f32x4 acc[4];
#pragma unroll
    for (int ct = 0; ct < 4; ++ct) acc[ct] = (f32x4){0.f, 0.f, 0.f, 0.f};

    const unsigned short* srcs[3] = {xbf, X1, X2};
    size_t abase = (size_t)v * 512 + (lane & 15) * 32 + (lane >> 4) * 8;
#pragma unroll
    for (int ks = 0; ks < 3; ++ks) {
        bf16x8 af = *(const bf16x8*)&srcs[ks][abase];
#pragma unroll
        for (int ct = 0; ct < 4; ++ct) {
            bf16x8 b = *(const bf16x8*)&sB[((ks * 4 + ct) * 64 + lane) * 8];
            acc[ct] = __builtin_amdgcn_mfma_f32_16x16x32_bf16(af, b, acc[ct], 0, 0, 0);
        }
    }
#pragma unroll
    for (int ct = 0; ct < 4; ++ct) {
        bf16x8 b = *(const bf16x8*)&sB[((12 + ct) * 64 + lane) * 8];
        acc[ct] = __builtin_amdgcn_mfma_f32_16x16x32_bf16(a3.h, b, acc[ct], 0, 0, 0);
    }

    // ---- BN partials: shfl-reduce the 4 lanes sharing (lane&15); per-wave non-atomic write ----
#pragma unroll
    for (int ct = 0; ct < 4; ++ct) {
        float ss = acc[ct].x + acc[ct].y + acc[ct].z + acc[ct].w;
        float qq = acc[ct].x * acc[ct].x + acc[ct].y * acc[ct].y
                 + acc[ct].z * acc[ct].z + acc[ct].w * acc[ct].w;
        ss += __shfl_xor(ss, 16); ss += __shfl_xor(ss, 32);
        qq += __shfl_xor(qq, 16); qq += __shfl_xor(qq, 32);
        if (lane < 16) {
            float* pw = &pout[(size_t)(blockIdx.x * 4 + wave) * 128];
            pw[ct * 16 + lane]      = ss;
            pw[64 + ct * 16 + lane] = qq;
        }
    }

    // ---- bounce C into LDS, coalesced Y write ----
#pragma unroll
    for (int ct = 0; ct < 4; ++ct) {
        int o = ct * 16 + (lane & 15);
        int bb = (lane >> 4) * 4;
        sY[wave * 1024 + (bb + 0) * 64 + o] = f2b(acc[ct].x);
        sY[wave * 1024 + (bb + 1) * 64 + o] = f2b(acc[ct].y);
        sY[wave * 1024 + (bb + 2) * 64 + o] = f2b(acc[ct].z);
        sY[wave * 1024 + (bb + 3) * 64 + o] = f2b(acc[ct].w);
    }
    __syncthreads();
    size_t ybase = (size_t)blockIdx.x * 4096 + t * 16;
    *(uint4*)&Y[ybase]     = *(const uint4*)&sY[t * 16];
    *(uint4*)&Y[ybase + 8] = *(const uint4*)&sY[t * 16 + 8];
}

// ---------------- reduce partials [49152][128] -> partials2[48][128] ----------------
__global__ __launch_bounds__(128) void k_bnred2(const float* __restrict__ P,
                                                float* __restrict__ partials2) {
    int t = threadIdx.x;   // 128
    size_t base = (size_t)blockIdx.x * 1024;
    float s = 0.f;
    for (int r = 0; r < 1024; ++r)
        s += P[(base + r) * 128 + t];
    partials2[blockIdx.x * 128 + t] = s;
}

// ---------------- finalize BN scale/shift from 48 partial rows ----------------
__global__ void k_bnfin(const float* __restrict__ partials2,
                        const float* __restrict__ gamma, const float* __restrict__ beta,
                        float* __restrict__ stats) {
    __shared__ float tot[128];
    int t = threadIdx.x;   // 128 threads
    float s = 0.f;
    for (int i = 0; i < 48; ++i) s += partials2[i * 128 + t];
    tot[t] = s;
    __syncthreads();
    if (t < 64) {
        float n = (float)(16 * V);
        float mean = tot[t] / n;
        float var = tot[64 + t] / n - mean * mean;
        float sc = gamma[t] * rsqrtf(var + EPS);
        stats[128 + t] = sc;
        stats[192 + t] = beta[t] - mean * sc;
    }
}

// ---------------- BN apply + ReLU + pool(4), bf16 y in ----------------
__global__ __launch_bounds__(256) void k_pool(const unsigned short* __restrict__ Y,
                                              const float* __restrict__ stats,
                                              float* __restrict__ out) {
    int id = blockIdx.x * blockDim.x + threadIdx.x;
    int o4 = id & 15;
    int b  = (id >> 4) & 15;
    int vp = id >> 8;
    float4 sc = *(const float4*)&stats[128 + o4 * 4];
    float4 sh = *(const float4*)&stats[192 + o4 * 4];
    float ax = 0.f, ay = 0.f, az = 0.f, aw = 0.f;
#pragma unroll
    for (int j = 0; j < 4; ++j) {
        ushort4 u = *(const ushort4*)&Y[(size_t)((vp * 4 + j) * 16 + b) * 64 + o4 * 4];
        float tx = b2f(u.x), ty = b2f(u.y), tz = b2f(u.z), tw = b2f(u.w);
        ax += fmaxf(fmaf(tx, sc.x, sh.x), 0.f);
        ay += fmaxf(fmaf(ty, sc.y, sh.y), 0.f);
        az += fmaxf(fmaf(tz, sc.z, sh.z), 0.f);
        aw += fmaxf(fmaf(tw, sc.w, sh.w), 0.f);
    }
    float4 res = {ax * 0.25f, ay * 0.25f, az * 0.25f, aw * 0.25f};
    *(float4*)&out[(size_t)((b * VOUT + vp) * 16 + o4) * 4] = res;
}

extern "C" void kernel_launch(void* const* d_in, const int* in_sizes, int n_in,
                              void* d_out, int out_size, void* d_ws, size_t ws_size,
                              hipStream_t stream) {
    const float* x     = (const float*)d_in[0];
    const float* vals  = (const float*)d_in[1];
    const float* W     = (const float*)d_in[2];
    const float* gamma = (const float*)d_in[3];
    const float* beta  = (const float*)d_in[4];
    const int*   rows  = (const int*)d_in[5];
    const int*   cols  = (const int*)d_in[6];
    float* out = (float*)d_out;

    char* ws = (char*)d_ws;
    unsigned short* xbf = (unsigned short*)ws;                    //  50,331,648 B
    unsigned short* X1  = (unsigned short*)(ws + 50331648UL);     //  50,331,648 B
    unsigned short* X2  = (unsigned short*)(ws + 100663296UL);    //  50,331,648 B
    unsigned short* Y   = (unsigned short*)(ws + 150994944UL);    // 100,663,296 B (ends 251,658,240)
    int*   rp    = (int*)(ws + 251658240UL);                      // 196,612 B (ends 251,854,852)
    float* stats = (float*)(ws + 251859968UL);                    // 1 KB
    unsigned short* Wfrag = (unsigned short*)(ws + 251860992UL);  // 16 KB (ends 251,877,376)
    float* pout  = (float*)(ws + 251877376UL);                    // 25,165,824 B (49152*128*4, ends 277,043,200)
    float* partials2 = (float*)(ws + 277043200UL);                // 24,576 B

    k_rowptr<<<193, 256, 0, stream>>>(rows, rp);
    k_xpose<<<V * 128 / 256, 256, 0, stream>>>(x, xbf);
    k_wconv<<<32, 256, 0, stream>>>(W, Wfrag);
    k_spmm1<<<V / 4, 256, 0, stream>>>(xbf, cols, vals, rp, X1);
    k_spmm2<<<V / 4, 256, 0, stream>>>(xbf, cols, vals, rp, X1, X2);
    k_cheb<<<V / 4, 256, 0, stream>>>(xbf, X1, X2, Wfrag, cols, vals, rp, Y, pout);
    k_bnred2<<<48, 128, 0, stream>>>(pout, partials2);
    k_bnfin<<<1, 128, 0, stream>>>(partials2, gamma, beta, stats);
    k_pool<<<12288, 256, 0, stream>>>(Y, stats, out);
}

// Round 15
// 326.667 us; speedup vs baseline: 1.3712x; 1.0745x over previous
//
#include <hip/hip_runtime.h>
#include <hip/hip_bf16.h>

#define V     49152
#define NNZ   442368
#define EPS   1e-5f
#define VOUT  12288

typedef __attribute__((ext_vector_type(8))) short bf16x8;
typedef __attribute__((ext_vector_type(4))) float f32x4;

__device__ __forceinline__ unsigned short f2b(float f) {
    __hip_bfloat16 h = __float2bfloat16(f);
    return *reinterpret_cast<unsigned short*>(&h);
}
__device__ __forceinline__ float b2f(unsigned short u) {
    return __uint_as_float((unsigned)u << 16);
}

// ---------------- prep: row_ptr binary search (blocks 0..192) + Wfrag conv (blocks 193..224) ----------------
__global__ __launch_bounds__(256) void k_prep(const int* __restrict__ rows,
                                              const float* __restrict__ W,
                                              int* __restrict__ rp,
                                              unsigned short* __restrict__ Wfrag) {
    if (blockIdx.x < 193) {
        int id = blockIdx.x * 256 + threadIdx.x;
        if (id <= V) {
            int lo = 0, hi = NNZ;
            while (lo < hi) {
                int m = (lo + hi) >> 1;
                if (rows[m] < id) lo = m + 1; else hi = m;
            }
            rp[id] = lo;
        }
    } else {
        int d = (blockIdx.x - 193) * 256 + threadIdx.x;    // 8192 total
        int j = d & 7, lane = (d >> 3) & 63, ct = (d >> 9) & 3, ks = d >> 11;
        int k128 = ks * 32 + (lane >> 4) * 8 + j;
        int o = ct * 16 + (lane & 15);
        Wfrag[d] = f2b(W[k128 * 64 + o]);
    }
}

// ---------------- transpose x [B,V,32] f32 -> xbf [V, b*32+i] bf16 ----------------
__global__ __launch_bounds__(256) void k_xpose(const float* __restrict__ x,
                                               unsigned short* __restrict__ xbf) {
    int id = blockIdx.x * 256 + threadIdx.x;   // V*128 ids
    int i4 = id & 7;
    int b  = (id >> 3) & 15;
    int v  = id >> 7;
    float4 q = *(const float4*)&x[((size_t)b * V + v) * 32 + i4 * 4];
    ushort4 u = {f2b(q.x), f2b(q.y), f2b(q.z), f2b(q.w)};
    *(ushort4*)&xbf[(size_t)v * 512 + b * 32 + i4 * 4] = u;
}

// gather macro body: 4-deep MLP unroll
#define GATHER_LOOP(SRC)                                                        \
    float a[8] = {0.f, 0.f, 0.f, 0.f, 0.f, 0.f, 0.f, 0.f};                      \
    int n = s;                                                                  \
    for (; n + 3 < e; n += 4) {                                                 \
        int c0 = cols[n], c1 = cols[n + 1], c2 = cols[n + 2], c3 = cols[n + 3]; \
        float w0 = vals[n], w1 = vals[n + 1], w2 = vals[n + 2], w3 = vals[n + 3]; \
        union { unsigned short u[8]; uint4 q; } l0, l1, l2, l3;                 \
        l0.q = *(const uint4*)&SRC[(size_t)c0 * 512 + f0];                      \
        l1.q = *(const uint4*)&SRC[(size_t)c1 * 512 + f0];                      \
        l2.q = *(const uint4*)&SRC[(size_t)c2 * 512 + f0];                      \
        l3.q = *(const uint4*)&SRC[(size_t)c3 * 512 + f0];                      \
        _Pragma("unroll")                                                       \
        for (int j = 0; j < 8; ++j) a[j] = fmaf(w0, b2f(l0.u[j]), a[j]);        \
        _Pragma("unroll")                                                       \
        for (int j = 0; j < 8; ++j) a[j] = fmaf(w1, b2f(l1.u[j]), a[j]);        \
        _Pragma("unroll")                                                       \
        for (int j = 0; j < 8; ++j) a[j] = fmaf(w2, b2f(l2.u[j]), a[j]);        \
        _Pragma("unroll")                                                       \
        for (int j = 0; j < 8; ++j) a[j] = fmaf(w3, b2f(l3.u[j]), a[j]);        \
    }                                                                           \
    for (; n < e; ++n) {                                                        \
        int c0 = cols[n];                                                       \
        float w0 = vals[n];                                                     \
        union { unsigned short u[8]; uint4 q; } l0;                             \
        l0.q = *(const uint4*)&SRC[(size_t)c0 * 512 + f0];                      \
        _Pragma("unroll")                                                       \
        for (int j = 0; j < 8; ++j) a[j] = fmaf(w0, b2f(l0.u[j]), a[j]);        \
    }

// ---------------- X1 = L @ X0 ----------------
__global__ __launch_bounds__(256) void k_spmm1(const unsigned short* __restrict__ xbf,
                                               const int* __restrict__ cols,
                                               const float* __restrict__ vals,
                                               const int* __restrict__ rp,
                                               unsigned short* __restrict__ X1) {
    int t = threadIdx.x;
    int wave = t >> 6, lane = t & 63;
    int v = blockIdx.x * 4 + wave;
    int f0 = lane * 8;
    int s = rp[v], e = rp[v + 1];
    GATHER_LOOP(xbf)
    union { unsigned short u[8]; uint4 q; } st;
#pragma unroll
    for (int j = 0; j < 8; ++j) st.u[j] = f2b(a[j]);
    *(uint4*)&X1[(size_t)v * 512 + f0] = st.q;
}

// ---------------- X2 = 2 L @ X1 - X0 ----------------
__global__ __launch_bounds__(256) void k_spmm2(const unsigned short* __restrict__ xbf,
                                               const int* __restrict__ cols,
                                               const float* __restrict__ vals,
                                               const int* __restrict__ rp,
                                               const unsigned short* __restrict__ X1,
                                               unsigned short* __restrict__ X2) {
    int t = threadIdx.x;
    int wave = t >> 6, lane = t & 63;
    int v = blockIdx.x * 4 + wave;
    int f0 = lane * 8;
    int s = rp[v], e = rp[v + 1];
    GATHER_LOOP(X1)
    union { unsigned short u[8]; uint4 q; } x0;
    x0.q = *(const uint4*)&xbf[(size_t)v * 512 + f0];
    union { unsigned short u[8]; uint4 q; } st;
#pragma unroll
    for (int j = 0; j < 8; ++j) st.u[j] = f2b(2.f * a[j] - b2f(x0.u[j]));
    *(uint4*)&X2[(size_t)v * 512 + f0] = st.q;
}

// ---- fused: X3 gather (regs, shfl to A-frag) + MFMA einsum + per-block BN partial + Y ----
// One wave per vertex. X3 never touches HBM. sY/sP alias into sB (dead after last B-read).
__global__ __launch_bounds__(256) void k_cheb(const unsigned short* __restrict__ xbf,
                                              const unsigned short* __restrict__ X1,
                                              const unsigned short* __restrict__ X2,
                                              const unsigned short* __restrict__ Wfrag,
                                              const int* __restrict__ cols,
                                              const float* __restrict__ vals,
                                              const int* __restrict__ rp,
                                              unsigned short* __restrict__ Y,
                                              float* __restrict__ pout) {
    __shared__ unsigned short sB[8192];   // 16 KB, fragment-ordered W; later aliased: sY (8 KB)
    __shared__ float sP[512];             // 2 KB per-wave BN partials

    int t = threadIdx.x;
    int wave = t >> 6, lane = t & 63;
    int v = blockIdx.x * 4 + wave;

    // stage Wfrag -> LDS (completes under the gather; barrier comes after gather)
#pragma unroll
    for (int m = 0; m < 4; ++m) {
        int d = t + m * 256;
        *(uint4*)&sB[d * 8] = *(const uint4*)&Wfrag[d * 8];
    }

    // ---- gather X3 row of v into registers (lane holds features [8*lane, 8*lane+8)) ----
    int f0 = lane * 8;
    int s = rp[v], e = rp[v + 1];
    GATHER_LOOP(X2)
    union { unsigned short u[8]; uint4 q; } p1;
    p1.q = *(const uint4*)&X1[(size_t)v * 512 + f0];
    // X3 = 2a - X1, packed to bf16 pairs for shfl
    uint4 packed;
    packed.x = (unsigned)f2b(2.f * a[0] - b2f(p1.u[0])) | ((unsigned)f2b(2.f * a[1] - b2f(p1.u[1])) << 16);
    packed.y = (unsigned)f2b(2.f * a[2] - b2f(p1.u[2])) | ((unsigned)f2b(2.f * a[3] - b2f(p1.u[3])) << 16);
    packed.z = (unsigned)f2b(2.f * a[4] - b2f(p1.u[4])) | ((unsigned)f2b(2.f * a[5] - b2f(p1.u[5])) << 16);
    packed.w = (unsigned)f2b(2.f * a[6] - b2f(p1.u[6])) | ((unsigned)f2b(2.f * a[7] - b2f(p1.u[7])) << 16);
    // A-frag lane m needs lane s(m) = (m&15)*4 + (m>>4)'s 8 features
    int src = (lane & 15) * 4 + (lane >> 4);
    union { uint4 q; bf16x8 h; } a3;
    a3.q.x = __shfl(packed.x, src);
    a3.q.y = __shfl(packed.y, src);
    a3.q.z = __shfl(packed.z, src);
    a3.q.w = __shfl(packed.w, src);

    __syncthreads();   // sB ready (staged long ago)

    // ---- MFMA: ks = 0,1,2 from global, ks = 3 from registers ----
    f32x4 acc[4];
#pragma unroll
    for (int ct = 0; ct < 4; ++ct) acc[ct] = (f32x4){0.f, 0.f, 0.f, 0.f};

    const unsigned short* srcs[3] = {xbf, X1, X2};
    size_t abase = (size_t)v * 512 + (lane & 15) * 32 + (lane >> 4) * 8;
#pragma unroll
    for (int ks = 0; ks < 3; ++ks) {
        bf16x8 af = *(const bf16x8*)&srcs[ks][abase];
#pragma unroll
        for (int ct = 0; ct < 4; ++ct) {
            bf16x8 b = *(const bf16x8*)&sB[((ks * 4 + ct) * 64 + lane) * 8];
            acc[ct] = __builtin_amdgcn_mfma_f32_16x16x32_bf16(af, b, acc[ct], 0, 0, 0);
        }
    }
#pragma unroll
    for (int ct = 0; ct < 4; ++ct) {
        bf16x8 b = *(const bf16x8*)&sB[((12 + ct) * 64 + lane) * 8];
        acc[ct] = __builtin_amdgcn_mfma_f32_16x16x32_bf16(a3.h, b, acc[ct], 0, 0, 0);
    }

    // ---- BN partials: shfl-reduce the 4 lanes sharing (lane&15), per-wave LDS slice ----
#pragma unroll
    for (int ct = 0; ct < 4; ++ct) {
        float ss = acc[ct].x + acc[ct].y + acc[ct].z + acc[ct].w;
        float qq = acc[ct].x * acc[ct].x + acc[ct].y * acc[ct].y
                 + acc[ct].z * acc[ct].z + acc[ct].w * acc[ct].w;
        ss += __shfl_xor(ss, 16); ss += __shfl_xor(ss, 32);
        qq += __shfl_xor(qq, 16); qq += __shfl_xor(qq, 32);
        if (lane < 16) {
            sP[wave * 128 + ct * 16 + lane]      = ss;
            sP[wave * 128 + 64 + ct * 16 + lane] = qq;
        }
    }

    // ---- bounce C into LDS (alias over sB — all B-frag reads are done), coalesced Y write ----
    __syncthreads();   // every wave finished its MFMA B-reads and sP writes
    unsigned short* sY = sB;
#pragma unroll
    for (int ct = 0; ct < 4; ++ct) {
        int o = ct * 16 + (lane & 15);
        int bb = (lane >> 4) * 4;
        sY[wave * 1024 + (bb + 0) * 64 + o] = f2b(acc[ct].x);
        sY[wave * 1024 + (bb + 1) * 64 + o] = f2b(acc[ct].y);
        sY[wave * 1024 + (bb + 2) * 64 + o] = f2b(acc[ct].z);
        sY[wave * 1024 + (bb + 3) * 64 + o] = f2b(acc[ct].w);
    }
    __syncthreads();
    size_t ybase = (size_t)blockIdx.x * 4096 + t * 16;
    *(uint4*)&Y[ybase]     = *(const uint4*)&sY[t * 16];
    *(uint4*)&Y[ybase + 8] = *(const uint4*)&sY[t * 16 + 8];

    // per-block non-atomic partial: sum the 4 wave slices
    if (t < 128)
        pout[(size_t)blockIdx.x * 128 + t] =
            sP[t] + sP[128 + t] + sP[256 + t] + sP[384 + t];
}

// ---------------- reduce partials [12288][128] -> partials2[48][128] ----------------
__global__ __launch_bounds__(128) void k_bnred2(const float* __restrict__ P,
                                                float* __restrict__ partials2) {
    int t = threadIdx.x;   // 128
    size_t base = (size_t)blockIdx.x * 256;
    float s = 0.f;
    for (int r = 0; r < 256; ++r)
        s += P[(base + r) * 128 + t];
    partials2[blockIdx.x * 128 + t] = s;
}

// ---------------- finalize BN scale/shift from 48 partial rows ----------------
__global__ void k_bnfin(const float* __restrict__ partials2,
                        const float* __restrict__ gamma, const float* __restrict__ beta,
                        float* __restrict__ stats) {
    __shared__ float tot[128];
    int t = threadIdx.x;   // 128 threads
    float s = 0.f;
    for (int i = 0; i < 48; ++i) s += partials2[i * 128 + t];
    tot[t] = s;
    __syncthreads();
    if (t < 64) {
        float n = (float)(16 * V);
        float mean = tot[t] / n;
        float var = tot[64 + t] / n - mean * mean;
        float sc = gamma[t] * rsqrtf(var + EPS);
        stats[128 + t] = sc;
        stats[192 + t] = beta[t] - mean * sc;
    }
}

// ---------------- BN apply + ReLU + pool(4), bf16 y in ----------------
__global__ __launch_bounds__(256) void k_pool(const unsigned short* __restrict__ Y,
                                              const float* __restrict__ stats,
                                              float* __restrict__ out) {
    int id = blockIdx.x * blockDim.x + threadIdx.x;
    int o4 = id & 15;
    int b  = (id >> 4) & 15;
    int vp = id >> 8;
    float4 sc = *(const float4*)&stats[128 + o4 * 4];
    float4 sh = *(const float4*)&stats[192 + o4 * 4];
    float ax = 0.f, ay = 0.f, az = 0.f, aw = 0.f;
#pragma unroll
    for (int j = 0; j < 4; ++j) {
        ushort4 u = *(const ushort4*)&Y[(size_t)((vp * 4 + j) * 16 + b) * 64 + o4 * 4];
        float tx = b2f(u.x), ty = b2f(u.y), tz = b2f(u.z), tw = b2f(u.w);
        ax += fmaxf(fmaf(tx, sc.x, sh.x), 0.f);
        ay += fmaxf(fmaf(ty, sc.y, sh.y), 0.f);
        az += fmaxf(fmaf(tz, sc.z, sh.z), 0.f);
        aw += fmaxf(fmaf(tw, sc.w, sh.w), 0.f);
    }
    float4 res = {ax * 0.25f, ay * 0.25f, az * 0.25f, aw * 0.25f};
    *(float4*)&out[(size_t)((b * VOUT + vp) * 16 + o4) * 4] = res;
}

extern "C" void kernel_launch(void* const* d_in, const int* in_sizes, int n_in,
                              void* d_out, int out_size, void* d_ws, size_t ws_size,
                              hipStream_t stream) {
    const float* x     = (const float*)d_in[0];
    const float* vals  = (const float*)d_in[1];
    const float* W     = (const float*)d_in[2];
    const float* gamma = (const float*)d_in[3];
    const float* beta  = (const float*)d_in[4];
    const int*   rows  = (const int*)d_in[5];
    const int*   cols  = (const int*)d_in[6];
    float* out = (float*)d_out;

    char* ws = (char*)d_ws;
    unsigned short* xbf = (unsigned short*)ws;                    //  50,331,648 B
    unsigned short* X1  = (unsigned short*)(ws + 50331648UL);     //  50,331,648 B
    unsigned short* X2  = (unsigned short*)(ws + 100663296UL);    //  50,331,648 B
    unsigned short* Y   = (unsigned short*)(ws + 150994944UL);    // 100,663,296 B (ends 251,658,240)
    int*   rp    = (int*)(ws + 251658240UL);                      // 196,612 B (ends 251,854,852)
    float* stats = (float*)(ws + 251859968UL);                    // 1 KB
    unsigned short* Wfrag = (unsigned short*)(ws + 251860992UL);  // 16 KB (ends 251,877,376)
    float* pout  = (float*)(ws + 251877376UL);                    // 6,291,456 B (ends 258,168,832)
    float* partials2 = (float*)(ws + 258168832UL);                // 24,576 B

    k_prep<<<225, 256, 0, stream>>>(rows, W, rp, Wfrag);
    k_xpose<<<V * 128 / 256, 256, 0, stream>>>(x, xbf);
    k_spmm1<<<V / 4, 256, 0, stream>>>(xbf, cols, vals, rp, X1);
    k_spmm2<<<V / 4, 256, 0, stream>>>(xbf, cols, vals, rp, X1, X2);
    k_cheb<<<V / 4, 256, 0, stream>>>(xbf, X1, X2, Wfrag, cols, vals, rp, Y, pout);
    k_bnred2<<<48, 128, 0, stream>>>(pout, partials2);
    k_bnfin<<<1, 128, 0, stream>>>(partials2, gamma, beta, stats);
    k_pool<<<12288, 256, 0, stream>>>(Y, stats, out);
}